// Round 18
// baseline (217.901 us; speedup 1.0000x reference)
//
#include <hip/hip_runtime.h>
#include <stdint.h>

typedef short bf16x8 __attribute__((ext_vector_type(8)));   // 8 bf16 in 4 VGPRs
typedef float f32x4 __attribute__((ext_vector_type(4)));
typedef unsigned short ushort_t;

#define RSQRT2_F 0.70710678118654752440f
#define QSCALE_F 0.18033688011114382f   /* 0.125 * log2(e) */

__device__ __forceinline__ ushort_t f2bf(float f) {
  union { float f; uint32_t u; } c; c.f = f;
  uint32_t u = c.u;
  uint32_t r = (u + 0x7fffu + ((u >> 16) & 1u)) >> 16;   // RNE
  return (ushort_t)r;
}
__device__ __forceinline__ float bf2f(ushort_t u) {
  union { uint32_t u; float f; } c; c.u = ((uint32_t)u) << 16;
  return c.f;
}
__device__ __forceinline__ uint32_t fbits(float f) {
  union { float f; uint32_t u; } c; c.f = f; return c.u;
}

__device__ __forceinline__ void gload_lds16(const void* g, void* l) {
  __builtin_amdgcn_global_load_lds(
      (const __attribute__((address_space(1))) void*)g,
      (__attribute__((address_space(3))) void*)l, 16, 0, 0);
}

// ---------------- converts ----------------
__global__ __launch_bounds__(256) void k_cvt_x(const float* __restrict__ x,
                                               ushort_t* __restrict__ xb) {
  int i = (blockIdx.x * 256 + threadIdx.x) * 4;
  float4 f = *(const float4*)(x + i);
  ushort4 o;
  o.x = f2bf(f.x); o.y = f2bf(f.y); o.z = f2bf(f.z); o.w = f2bf(f.w);
  *(ushort4*)(xb + i) = o;
}

// Wt layout: [1536][1024]; rows 0..511 = Q cols (scaled by 0.125*log2e), 512..1023 = K, 1024..1535 = V
__global__ __launch_bounds__(256) void k_build_wqkv(const float* __restrict__ Wqk,
                                                    const float* __restrict__ bqk,
                                                    const float* __restrict__ Wv,
                                                    const float* __restrict__ bv,
                                                    ushort_t* __restrict__ Wt,
                                                    float* __restrict__ biasAll) {
  int k = blockIdx.x * 256 + threadIdx.x;  // 0..1023
  int n = blockIdx.y;                      // 0..1535
  float w, bb;
  if (n < 512)       { w = Wqk[(size_t)k * 1024 + 2 * n] * QSCALE_F;     bb = bqk[2 * n] * QSCALE_F; }
  else if (n < 1024) { w = Wqk[(size_t)k * 1024 + 2 * (n - 512) + 1];    bb = bqk[2 * (n - 512) + 1]; }
  else               { w = Wv[(size_t)k * 512 + (n - 1024)];             bb = bv[n - 1024]; }
  Wt[(size_t)n * 1024 + k] = f2bf(w);
  if (k == 0) biasAll[n] = bb;
}

__global__ __launch_bounds__(256) void k_build_wout(const float* __restrict__ Wout,
                                                    ushort_t* __restrict__ Wt) {
  int k = blockIdx.x * 256 + threadIdx.x;  // 0..511
  int n = blockIdx.y;                      // 0..1023
  Wt[(size_t)n * 512 + k] = f2bf(Wout[(size_t)k * 1024 + n]);
}

// ---------------- GEMM: C[M,N] = A[M,K](bf16) @ Bt[N,K](bf16)^T + bias ----------------
// r1's measured-good structure (single-buffer LDS, two barriers, 2D grid, r14 epilogue)
// with BK=64: 4 staging issues/operand, 32 MFMA per K-step, half the barriers.
template <int MODE>
__global__ __launch_bounds__(256) void k_gemm_bt(
    const ushort_t* __restrict__ A, const ushort_t* __restrict__ Bt,
    const float* __restrict__ bias,
    ushort_t* __restrict__ out0, ushort_t* __restrict__ out1, ushort_t* __restrict__ out2,
    int M, int N, int K) {
  __shared__ __align__(16) ushort_t As[8][128][8];  // [k/8][row][k%8]  16KB
  __shared__ __align__(16) ushort_t Bs[8][128][8];  // 16KB
  const int t = threadIdx.x;
  const int lane = t & 63;
  const int wave = t >> 6;
  const int m0 = blockIdx.x * 128, n0 = blockIdx.y * 128;
  const int wm = (wave >> 1) * 64, wn = (wave & 1) * 64;
  const int lg = lane >> 4, lr = lane & 15;

  const int srow = t & 127, sg = t >> 7;  // staging: row 0..127, g0 0..1 (issue i adds 2i)
  const ushort_t* gA = A + (size_t)(m0 + srow) * K + sg * 8;
  const ushort_t* gB = Bt + (size_t)(n0 + srow) * K + sg * 8;

  f32x4 acc[4][4] = {};

  for (int k0 = 0; k0 < K; k0 += 64) {
    __syncthreads();
#pragma unroll
    for (int i = 0; i < 4; i++) {
      gload_lds16(gA + k0 + 16 * i, &As[sg + 2 * i][srow][0]);
      gload_lds16(gB + k0 + 16 * i, &Bs[sg + 2 * i][srow][0]);
    }
    __syncthreads();
    bf16x8 af[2][4], bfr[2][4];
#pragma unroll
    for (int kk = 0; kk < 2; kk++) {
#pragma unroll
      for (int mi = 0; mi < 4; mi++) af[kk][mi] = *(const bf16x8*)&As[kk * 4 + lg][wm + mi * 16 + lr][0];
#pragma unroll
      for (int ni = 0; ni < 4; ni++) bfr[kk][ni] = *(const bf16x8*)&Bs[kk * 4 + lg][wn + ni * 16 + lr][0];
    }
#pragma unroll
    for (int kk = 0; kk < 2; kk++)
#pragma unroll
      for (int mi = 0; mi < 4; mi++)
#pragma unroll
        for (int ni = 0; ni < 4; ni++)
          acc[mi][ni] = __builtin_amdgcn_mfma_f32_16x16x32_bf16(af[kk][mi], bfr[kk][ni], acc[mi][ni], 0, 0, 0);
  }

#pragma unroll
  for (int mi = 0; mi < 4; mi++) {
    int rowb = m0 + wm + mi * 16 + (lane >> 4) * 4;
#pragma unroll
    for (int ni = 0; ni < 4; ni++) {
      int col = n0 + wn + ni * 16 + lr;
      float bc = bias[col];
#pragma unroll
      for (int reg = 0; reg < 4; reg++) {
        int row = rowb + reg;
        float v = acc[mi][ni][reg] + bc;
        if (MODE == 0) {
          if (col < 512) {
            out0[(size_t)row * 512 + col] = f2bf(v);
          } else if (col < 1024) {
            out1[(size_t)row * 512 + (col - 512)] = f2bf(v);
          } else {
            int hd = col - 1024;
            int bb = row >> 12, s = row & 4095;
            out2[((size_t)(bb << 9) + hd) * 4096 + s] = f2bf(v);
          }
        } else {
          out0[(size_t)row * 1024 + col] = f2bf(v);
        }
      }
    }
  }
}

// ---------------- flash attention (no-max; 4 waves x 64q; KVBLK=128 x 2 sub-steps; split2) ----
// r14-verified datapath; the 64-j body runs TWICE per staged 128-j tile (ss=0,1), halving
// barrier count (32 -> 16 per block). LDS 72KB (2 blocks/CU, matching the register limit).
__global__ __launch_bounds__(256, 2) void k_attn(const ushort_t* __restrict__ Qb,
                                                 const ushort_t* __restrict__ Kb,
                                                 const ushort_t* __restrict__ Vt,
                                                 ushort_t* __restrict__ O0,
                                                 ushort_t* __restrict__ O1,
                                                 float* __restrict__ lpart) {
  __shared__ __align__(16) ushort_t Ks[2][8][128][8];   // [buf][d/8][j][d%8]  32KB
  __shared__ __align__(16) ushort_t Vs[2][16][64][8];   // [buf][j/8][d][j%8]  32KB
  __shared__ __align__(16) ushort_t Pl[4][1024];        // per-wave single slot  8KB
  const int S = 4096;
  const int t = threadIdx.x, lane = t & 63, wave = t >> 6;
  const int lg = lane >> 4, lr = lane & 15;

  const int bid = blockIdx.x;
  const int xcd = bid & 7, idx = bid >> 3;           // idx 0..63
  const int bh = (xcd << 1) | (idx >> 5);            // 0..15, locked to one XCD
  const int rem = idx & 31;
  const int qb = rem >> 1;                            // 0..15 (256-q block)
  const int half = rem & 1;                           // KV half
  const int b = bh >> 3, h = bh & 7;
  const int qbase = qb * 256 + wave * 64;
  const int kvbase = half * 2048;

  // Q fragments for all four su (scale+log2e pre-folded into W_q)
  bf16x8 qf[4][2];
#pragma unroll
  for (int su = 0; su < 4; su++) {
    const ushort_t* qp = Qb + ((size_t)(b * S + qbase + su * 16 + lr)) * 512 + h * 64 + lg * 8;
    qf[su][0] = *(const bf16x8*)qp;
    qf[su][1] = *(const bf16x8*)(qp + 32);
  }

  // staging: K chunk c=i*256+t -> kg=2i+(t>>7), j=t&127 ; V chunk c=i*256+t -> jg=4i+(t>>6), d=t&63
  const int srow = t & 127, sg = t >> 7;
  const int vd = t & 63, vg = t >> 6;
  const ushort_t* gK = Kb + ((size_t)(b * S) + srow) * 512 + h * 64 + sg * 8;
  const ushort_t* gV = Vt + ((size_t)(bh * 64) + vd) * 4096 + vg * 8;

  const bf16x8 vones = {(short)0x3F80, (short)0x3F80, (short)0x3F80, (short)0x3F80,
                        (short)0x3F80, (short)0x3F80, (short)0x3F80, (short)0x3F80};

  // precomputed P LDS offsets (loop-invariant)
  int poff[4], pread[2];
#pragma unroll
  for (int nt = 0; nt < 4; nt++) poff[nt] = (lr * 128 + nt * 32 + lg * 8) ^ ((lr & 7) << 4);
#pragma unroll
  for (int kc = 0; kc < 2; kc++) pread[kc] = (lr * 128 + kc * 64 + lg * 16) ^ ((lr & 7) << 4);

  f32x4 of[4][4] = {};
  f32x4 of_sum[4] = {};

#define ATTN_STAGE(kv0, bsel)                                              \
  do {                                                                     \
    _Pragma("unroll")                                                      \
    for (int i = 0; i < 4; i++) {                                          \
      gload_lds16(gK + (size_t)(kv0) * 512 + i * 16, &Ks[bsel][sg + 2 * i][srow][0]); \
      gload_lds16(gV + (kv0) + i * 32, &Vs[bsel][vg + 4 * i][vd][0]);      \
    }                                                                      \
  } while (0)

  ATTN_STAGE(kvbase, 0);
  __syncthreads();
  int buf = 0;

  for (int kv0 = kvbase; kv0 < kvbase + 2048; kv0 += 128) {
    if (kv0 + 128 < kvbase + 2048) ATTN_STAGE(kv0 + 128, buf ^ 1);

#pragma unroll
    for (int ss = 0; ss < 2; ss++) {
      // S^T = K Q^T : lane owns q = lr; holds j = ss*64 + nt*16 + lg*4 + r (all su share kf)
      f32x4 sf[4][4];
      __builtin_amdgcn_s_setprio(1);
#pragma unroll
      for (int nt = 0; nt < 4; nt++) {
        bf16x8 kf0 = *(const bf16x8*)&Ks[buf][lg][ss * 64 + nt * 16 + lr][0];
        bf16x8 kf1 = *(const bf16x8*)&Ks[buf][4 + lg][ss * 64 + nt * 16 + lr][0];
#pragma unroll
        for (int su = 0; su < 4; su++) {
          f32x4 z = {};
          z = __builtin_amdgcn_mfma_f32_16x16x32_bf16(kf0, qf[su][0], z, 0, 0, 0);
          sf[su][nt] = __builtin_amdgcn_mfma_f32_16x16x32_bf16(kf1, qf[su][1], z, 0, 0, 0);
        }
      }
      __builtin_amdgcn_s_setprio(0);

      // P = exp2(s) directly; pack 4 consecutive j as 2 u32 (truncate-to-bf16).
      // Single P slot per wave: su-sequential write->read (wave-local DS ordering; verified).
      bf16x8 pf[4][2];
#pragma unroll
      for (int su = 0; su < 4; su++) {
        char* Pb = (char*)&Pl[wave][0];
#pragma unroll
        for (int nt = 0; nt < 4; nt++) {
          float p0 = __builtin_amdgcn_exp2f(sf[su][nt][0]);
          float p1 = __builtin_amdgcn_exp2f(sf[su][nt][1]);
          float p2 = __builtin_amdgcn_exp2f(sf[su][nt][2]);
          float p3 = __builtin_amdgcn_exp2f(sf[su][nt][3]);
          uint32_t w0 = (fbits(p0) >> 16) | (fbits(p1) & 0xffff0000u);
          uint32_t w1 = (fbits(p2) >> 16) | (fbits(p3) & 0xffff0000u);
          *(uint2*)(Pb + poff[nt]) = make_uint2(w0, w1);
        }
#pragma unroll
        for (int kc = 0; kc < 2; kc++) pf[su][kc] = *(const bf16x8*)(Pb + pread[kc]);
      }

      // O += P V ; l += P * ones   (all su share vf)
      __builtin_amdgcn_s_setprio(1);
#pragma unroll
      for (int dt = 0; dt < 4; dt++) {
        bf16x8 vf0 = *(const bf16x8*)&Vs[buf][ss * 8 + lg][dt * 16 + lr][0];
        bf16x8 vf1 = *(const bf16x8*)&Vs[buf][ss * 8 + 4 + lg][dt * 16 + lr][0];
#pragma unroll
        for (int su = 0; su < 4; su++) {
          of[su][dt] = __builtin_amdgcn_mfma_f32_16x16x32_bf16(pf[su][0], vf0, of[su][dt], 0, 0, 0);
          of[su][dt] = __builtin_amdgcn_mfma_f32_16x16x32_bf16(pf[su][1], vf1, of[su][dt], 0, 0, 0);
        }
      }
#pragma unroll
      for (int su = 0; su < 4; su++) {
        of_sum[su] = __builtin_amdgcn_mfma_f32_16x16x32_bf16(pf[su][0], vones, of_sum[su], 0, 0, 0);
        of_sum[su] = __builtin_amdgcn_mfma_f32_16x16x32_bf16(pf[su][1], vones, of_sum[su], 0, 0, 0);
      }
      __builtin_amdgcn_s_setprio(0);
    }

    __syncthreads();   // drains stage vmcnt + frag lgkmcnt; safe to swap buffers
    buf ^= 1;
  }
#undef ATTN_STAGE

  // epilogue: unnormalized partials into the half's buffer (rows b*4096+q)
  ushort_t* Opw = (half ? O1 : O0) + (size_t)b * 4096 * 512;
#pragma unroll
  for (int su = 0; su < 4; su++) {
#pragma unroll
    for (int dt = 0; dt < 4; dt++)
#pragma unroll
      for (int r = 0; r < 4; r++) {
        int q = qbase + su * 16 + lg * 4 + r;
        Opw[(size_t)q * 512 + h * 64 + dt * 16 + lr] = f2bf(of[su][dt][r]);
      }
    if (lr == 0) {
#pragma unroll
      for (int r = 0; r < 4; r++) {
        int q = qbase + su * 16 + lg * 4 + r;
        lpart[(((size_t)half * 2 + b) * 8 + h) * 4096 + q] = of_sum[su][r];
      }
    }
  }
}

// ---------------- merge partials: O = (O0+O1)/(l0+l1) ----------------
__global__ __launch_bounds__(128) void k_merge(const ushort_t* __restrict__ O0,
                                               const ushort_t* __restrict__ O1,
                                               const float* __restrict__ lpart,
                                               ushort_t* __restrict__ Ob) {
  const int row = blockIdx.x;          // b*4096 + q
  const int t = threadIdx.x;
  const int col = t * 4;
  const int b = row >> 12, q = row & 4095;
  const int h = col >> 6;
  float l = lpart[(((size_t)0 * 2 + b) * 8 + h) * 4096 + q] +
            lpart[(((size_t)1 * 2 + b) * 8 + h) * 4096 + q];
  float inv = 1.0f / l;
  ushort4 a0 = *(const ushort4*)(O0 + (size_t)row * 512 + col);
  ushort4 a1 = *(const ushort4*)(O1 + (size_t)row * 512 + col);
  ushort4 o;
  o.x = f2bf((bf2f(a0.x) + bf2f(a1.x)) * inv);
  o.y = f2bf((bf2f(a0.y) + bf2f(a1.y)) * inv);
  o.z = f2bf((bf2f(a0.z) + bf2f(a1.z)) * inv);
  o.w = f2bf((bf2f(a0.w) + bf2f(a1.w)) * inv);
  *(ushort4*)(Ob + (size_t)row * 512 + col) = o;
}

// ---------------- LayerNorm + residual ----------------
__global__ __launch_bounds__(256) void k_ln(const ushort_t* __restrict__ ypre,
                                            const float* __restrict__ x,
                                            const float* __restrict__ gamma,
                                            const float* __restrict__ beta,
                                            float* __restrict__ out) {
  __shared__ float red[8];
  const int row = blockIdx.x, t = threadIdx.x;
  const ushort_t* yr = ypre + (size_t)row * 1024;
  ushort4 u = *(const ushort4*)(yr + t * 4);
  float v0 = bf2f(u.x), v1 = bf2f(u.y), v2 = bf2f(u.z), v3 = bf2f(u.w);
  float s = v0 + v1 + v2 + v3;
  float sq = v0 * v0 + v1 * v1 + v2 * v2 + v3 * v3;
#pragma unroll
  for (int m = 32; m; m >>= 1) { s += __shfl_xor(s, m, 64); sq += __shfl_xor(sq, m, 64); }
  if ((t & 63) == 0) { red[t >> 6] = s; red[4 + (t >> 6)] = sq; }
  __syncthreads();
  s = red[0] + red[1] + red[2] + red[3];
  sq = red[4] + red[5] + red[6] + red[7];
  float mu = s * (1.f / 1024.f);
  float var = sq * (1.f / 1024.f) - mu * mu;
  float inv = rsqrtf(var + 1e-5f);
  int c = t * 4;
  float4 xf = *(const float4*)(x + (size_t)row * 1024 + c);
  float4 o;
  o.x = ((v0 - mu) * inv * gamma[c + 0] + beta[c + 0] + xf.x) * RSQRT2_F;
  o.y = ((v1 - mu) * inv * gamma[c + 1] + beta[c + 1] + xf.y) * RSQRT2_F;
  o.z = ((v2 - mu) * inv * gamma[c + 2] + beta[c + 2] + xf.z) * RSQRT2_F;
  o.w = ((v3 - mu) * inv * gamma[c + 3] + beta[c + 3] + xf.w) * RSQRT2_F;
  *(float4*)(out + (size_t)row * 1024 + c) = o;
}

extern "C" void kernel_launch(void* const* d_in, const int* in_sizes, int n_in,
                              void* d_out, int out_size, void* d_ws, size_t ws_size,
                              hipStream_t stream) {
  (void)in_sizes; (void)n_in; (void)out_size; (void)ws_size;
  const float* x     = (const float*)d_in[0];
  const float* Wqk   = (const float*)d_in[1];
  const float* bqk   = (const float*)d_in[2];
  const float* Wv    = (const float*)d_in[3];
  const float* bv    = (const float*)d_in[4];
  const float* Wout  = (const float*)d_in[5];
  const float* bout  = (const float*)d_in[6];
  const float* gamma = (const float*)d_in[7];
  const float* beta  = (const float*)d_in[8];
  float* out = (float*)d_out;

  char* ws = (char*)d_ws;
  size_t off = 0;
  auto alloc = [&](size_t bytes) {
    off = (off + 255) & ~(size_t)255;
    void* p = ws + off;
    off += bytes;
    return p;
  };
  ushort_t* xb    = (ushort_t*)alloc(8192ull * 1024 * 2);   // O0,O1 partials after GEMM0; ypre after merge
  ushort_t* Wqkvt = (ushort_t*)alloc(1536ull * 1024 * 2);
  float*    biasA = (float*)   alloc(1536ull * 4);
  ushort_t* Woutt = (ushort_t*)alloc(1024ull * 512 * 2);
  ushort_t* Qb    = (ushort_t*)alloc(8192ull * 512 * 2);    // Q; merged O after attn
  ushort_t* Kbuf  = (ushort_t*)alloc(8192ull * 512 * 2);
  ushort_t* Vtb   = (ushort_t*)alloc(1024ull * 4096 * 2);
  float*    lpart = (float*)   alloc(2ull * 2 * 8 * 4096 * 4);
  ushort_t* O0    = xb;                    // half 0 (first 8MB of xb)
  ushort_t* O1    = xb + 8192ull * 512;    // half 1 (second 8MB of xb)
  ushort_t* Obm   = Qb;                    // merged O (Qb dead after attn)
  ushort_t* ypre  = xb;                    // GEMM1 output (xb dead after merge)

  k_cvt_x<<<8192, 256, 0, stream>>>(x, xb);
  k_build_wqkv<<<dim3(4, 1536), 256, 0, stream>>>(Wqk, bqk, Wv, bv, Wqkvt, biasA);
  k_build_wout<<<dim3(2, 1024), 256, 0, stream>>>(Wout, Woutt);
  k_gemm_bt<0><<<dim3(64, 12), 256, 0, stream>>>(xb, Wqkvt, biasA, Qb, Kbuf, Vtb, 8192, 1536, 1024);
  k_attn<<<512, 256, 0, stream>>>(Qb, Kbuf, Vtb, O0, O1, lpart);
  k_merge<<<8192, 128, 0, stream>>>(O0, O1, lpart, Obm);
  k_gemm_bt<1><<<dim3(64, 8), 256, 0, stream>>>(Obm, Woutt, bout, ypre, nullptr, nullptr, 8192, 1024, 512);
  k_ln<<<8192, 256, 0, stream>>>(ypre, x, gamma, beta, out);
}

// Round 19
// 202.171 us; speedup vs baseline: 1.0778x; 1.0778x over previous
//
#include <hip/hip_runtime.h>
#include <stdint.h>

typedef short bf16x8 __attribute__((ext_vector_type(8)));   // 8 bf16 in 4 VGPRs
typedef float f32x4 __attribute__((ext_vector_type(4)));
typedef unsigned short ushort_t;

#define RSQRT2_F 0.70710678118654752440f
#define QSCALE_F 0.18033688011114382f   /* 0.125 * log2(e) */

__device__ __forceinline__ ushort_t f2bf(float f) {
  union { float f; uint32_t u; } c; c.f = f;
  uint32_t u = c.u;
  uint32_t r = (u + 0x7fffu + ((u >> 16) & 1u)) >> 16;   // RNE
  return (ushort_t)r;
}
__device__ __forceinline__ float bf2f(ushort_t u) {
  union { uint32_t u; float f; } c; c.u = ((uint32_t)u) << 16;
  return c.f;
}
__device__ __forceinline__ uint32_t fbits(float f) {
  union { float f; uint32_t u; } c; c.f = f; return c.u;
}

__device__ __forceinline__ void gload_lds16(const void* g, void* l) {
  __builtin_amdgcn_global_load_lds(
      (const __attribute__((address_space(1))) void*)g,
      (__attribute__((address_space(3))) void*)l, 16, 0, 0);
}

// ---------------- converts ----------------
__global__ __launch_bounds__(256) void k_cvt_x(const float* __restrict__ x,
                                               ushort_t* __restrict__ xb) {
  int i = (blockIdx.x * 256 + threadIdx.x) * 4;
  float4 f = *(const float4*)(x + i);
  ushort4 o;
  o.x = f2bf(f.x); o.y = f2bf(f.y); o.z = f2bf(f.z); o.w = f2bf(f.w);
  *(ushort4*)(xb + i) = o;
}

// Wt layout: [1536][1024]; rows 0..511 = Q cols (scaled by 0.125*log2e), 512..1023 = K, 1024..1535 = V
__global__ __launch_bounds__(256) void k_build_wqkv(const float* __restrict__ Wqk,
                                                    const float* __restrict__ bqk,
                                                    const float* __restrict__ Wv,
                                                    const float* __restrict__ bv,
                                                    ushort_t* __restrict__ Wt,
                                                    float* __restrict__ biasAll) {
  int k = blockIdx.x * 256 + threadIdx.x;  // 0..1023
  int n = blockIdx.y;                      // 0..1535
  float w, bb;
  if (n < 512)       { w = Wqk[(size_t)k * 1024 + 2 * n] * QSCALE_F;     bb = bqk[2 * n] * QSCALE_F; }
  else if (n < 1024) { w = Wqk[(size_t)k * 1024 + 2 * (n - 512) + 1];    bb = bqk[2 * (n - 512) + 1]; }
  else               { w = Wv[(size_t)k * 512 + (n - 1024)];             bb = bv[n - 1024]; }
  Wt[(size_t)n * 1024 + k] = f2bf(w);
  if (k == 0) biasAll[n] = bb;
}

__global__ __launch_bounds__(256) void k_build_wout(const float* __restrict__ Wout,
                                                    ushort_t* __restrict__ Wt) {
  int k = blockIdx.x * 256 + threadIdx.x;  // 0..511
  int n = blockIdx.y;                      // 0..1023
  Wt[(size_t)n * 512 + k] = f2bf(Wout[(size_t)k * 1024 + n]);
}

// ---------------- GEMM: C[M,N] = A[M,K](bf16) @ Bt[N,K](bf16)^T + bias ----------------
// r1/r14 measured-good structure (single-buffer LDS, BK=32, two barriers, scalar-store
// epilogue) + SUPERTILE block remap: consecutive 4*nby blocks cover a 4-m-tile A band x
// all n-tiles -> A band (1MB) + B panel stay L2-resident; A re-read drops ~12x.
template <int MODE>
__global__ __launch_bounds__(256) void k_gemm_bt(
    const ushort_t* __restrict__ A, const ushort_t* __restrict__ Bt,
    const float* __restrict__ bias,
    ushort_t* __restrict__ out0, ushort_t* __restrict__ out1, ushort_t* __restrict__ out2,
    int M, int N, int K) {
  __shared__ __align__(16) ushort_t As[4][128][8];  // [k/8][row][k%8]
  __shared__ __align__(16) ushort_t Bs[4][128][8];
  const int t = threadIdx.x;
  const int lane = t & 63;
  const int wave = t >> 6;

  // supertile remap (pure reorder; correctness-invariant)
  const int id = blockIdx.y * gridDim.x + blockIdx.x;   // x fastest in dispatch
  const int nby = gridDim.y;
  const int per = 4 * nby;
  const int sid = id / per, w = id % per;
  const int mt = sid * 4 + (w & 3), nt = w >> 2;
  const int m0 = mt * 128, n0 = nt * 128;

  const int wm = (wave >> 1) * 64, wn = (wave & 1) * 64;
  const int lg = lane >> 4, lr = lane & 15;

  const int srow = t & 127, sg = t >> 7;  // staging: row 0..127, g0 0..1
  ushort_t* lA0 = &As[sg][srow][0];
  ushort_t* lA1 = &As[sg + 2][srow][0];
  ushort_t* lB0 = &Bs[sg][srow][0];
  ushort_t* lB1 = &Bs[sg + 2][srow][0];
  const ushort_t* gA = A + (size_t)(m0 + srow) * K + sg * 8;
  const ushort_t* gB = Bt + (size_t)(n0 + srow) * K + sg * 8;

  f32x4 acc[4][4] = {};

  for (int k0 = 0; k0 < K; k0 += 32) {
    __syncthreads();
    gload_lds16(gA + k0, lA0);
    gload_lds16(gA + k0 + 16, lA1);
    gload_lds16(gB + k0, lB0);
    gload_lds16(gB + k0 + 16, lB1);
    __syncthreads();
    bf16x8 af[4], bfr[4];
#pragma unroll
    for (int mi = 0; mi < 4; mi++) af[mi] = *(const bf16x8*)&As[lg][wm + mi * 16 + lr][0];
#pragma unroll
    for (int ni = 0; ni < 4; ni++) bfr[ni] = *(const bf16x8*)&Bs[lg][wn + ni * 16 + lr][0];
#pragma unroll
    for (int mi = 0; mi < 4; mi++)
#pragma unroll
      for (int ni = 0; ni < 4; ni++)
        acc[mi][ni] = __builtin_amdgcn_mfma_f32_16x16x32_bf16(af[mi], bfr[ni], acc[mi][ni], 0, 0, 0);
  }

#pragma unroll
  for (int mi = 0; mi < 4; mi++) {
    int rowb = m0 + wm + mi * 16 + (lane >> 4) * 4;
#pragma unroll
    for (int ni = 0; ni < 4; ni++) {
      int col = n0 + wn + ni * 16 + lr;
      float bc = bias[col];
#pragma unroll
      for (int reg = 0; reg < 4; reg++) {
        int row = rowb + reg;
        float v = acc[mi][ni][reg] + bc;
        if (MODE == 0) {
          if (col < 512) {
            out0[(size_t)row * 512 + col] = f2bf(v);
          } else if (col < 1024) {
            out1[(size_t)row * 512 + (col - 512)] = f2bf(v);
          } else {
            int hd = col - 1024;
            int bb = row >> 12, s = row & 4095;
            out2[((size_t)(bb << 9) + hd) * 4096 + s] = f2bf(v);
          }
        } else {
          out0[(size_t)row * 1024 + col] = f2bf(v);
        }
      }
    }
  }
}

// ---------------- flash attention (no-max; 4 waves x 64q; KVBLK=64; KV-split x2) ----------------
// r14's verified 89us kernel, byte-identical.
__global__ __launch_bounds__(256, 2) void k_attn(const ushort_t* __restrict__ Qb,
                                                 const ushort_t* __restrict__ Kb,
                                                 const ushort_t* __restrict__ Vt,
                                                 ushort_t* __restrict__ O0,
                                                 ushort_t* __restrict__ O1,
                                                 float* __restrict__ lpart) {
  __shared__ __align__(16) ushort_t Ks[2][8][64][8];   // [buf][d/8][j][d%8]  16KB
  __shared__ __align__(16) ushort_t Vs[2][8][64][8];   // [buf][j/8][d][j%8]  16KB
  __shared__ __align__(16) ushort_t Pl[4][1024];       // per-wave single slot  8KB
  const int S = 4096;
  const int t = threadIdx.x, lane = t & 63, wave = t >> 6;
  const int lg = lane >> 4, lr = lane & 15;

  const int bid = blockIdx.x;
  const int xcd = bid & 7, idx = bid >> 3;           // idx 0..63
  const int bh = (xcd << 1) | (idx >> 5);            // 0..15, locked to one XCD
  const int rem = idx & 31;
  const int qb = rem >> 1;                            // 0..15 (256-q block)
  const int half = rem & 1;                           // KV half
  const int b = bh >> 3, h = bh & 7;
  const int qbase = qb * 256 + wave * 64;
  const int kvbase = half * 2048;

  // Q fragments for all four su (scale+log2e pre-folded into W_q)
  bf16x8 qf[4][2];
#pragma unroll
  for (int su = 0; su < 4; su++) {
    const ushort_t* qp = Qb + ((size_t)(b * S + qbase + su * 16 + lr)) * 512 + h * 64 + lg * 8;
    qf[su][0] = *(const bf16x8*)qp;
    qf[su][1] = *(const bf16x8*)(qp + 32);
  }

  // staging (256 threads): thread t -> chunk (cg = t>>6, cj = t&63); second issue cg+4
  const int cj = t & 63, cg = t >> 6;
  const ushort_t* gK = Kb + ((size_t)b * S + cj) * 512 + h * 64 + cg * 8;
  const ushort_t* gV = Vt + ((size_t)bh * 64 + cj) * 4096 + cg * 8;

  const bf16x8 vones = {(short)0x3F80, (short)0x3F80, (short)0x3F80, (short)0x3F80,
                        (short)0x3F80, (short)0x3F80, (short)0x3F80, (short)0x3F80};

  // precomputed P LDS offsets (loop-invariant)
  int poff[4], pread[2];
#pragma unroll
  for (int nt = 0; nt < 4; nt++) poff[nt] = (lr * 128 + nt * 32 + lg * 8) ^ ((lr & 7) << 4);
#pragma unroll
  for (int kc = 0; kc < 2; kc++) pread[kc] = (lr * 128 + kc * 64 + lg * 16) ^ ((lr & 7) << 4);

  f32x4 of[4][4] = {};
  f32x4 of_sum[4] = {};

#define ATTN_STAGE(kv0, bsel)                                         \
  do {                                                                \
    gload_lds16(gK + (size_t)(kv0) * 512, &Ks[bsel][cg][cj][0]);      \
    gload_lds16(gK + (size_t)(kv0) * 512 + 32, &Ks[bsel][cg + 4][cj][0]); \
    gload_lds16(gV + (kv0), &Vs[bsel][cg][cj][0]);                    \
    gload_lds16(gV + (kv0) + 32, &Vs[bsel][cg + 4][cj][0]);           \
  } while (0)

  ATTN_STAGE(kvbase, 0);
  __syncthreads();
  int buf = 0;

  for (int kv0 = kvbase; kv0 < kvbase + 2048; kv0 += 64) {
    if (kv0 + 64 < kvbase + 2048) ATTN_STAGE(kv0 + 64, buf ^ 1);

    // S^T = K Q^T : lane owns q = lr; holds j = nt*16 + lg*4 + r   (all su share kf)
    f32x4 sf[4][4];
    __builtin_amdgcn_s_setprio(1);
#pragma unroll
    for (int nt = 0; nt < 4; nt++) {
      bf16x8 kf0 = *(const bf16x8*)&Ks[buf][lg][nt * 16 + lr][0];
      bf16x8 kf1 = *(const bf16x8*)&Ks[buf][4 + lg][nt * 16 + lr][0];
#pragma unroll
      for (int su = 0; su < 4; su++) {
        f32x4 z = {};
        z = __builtin_amdgcn_mfma_f32_16x16x32_bf16(kf0, qf[su][0], z, 0, 0, 0);
        sf[su][nt] = __builtin_amdgcn_mfma_f32_16x16x32_bf16(kf1, qf[su][1], z, 0, 0, 0);
      }
    }
    __builtin_amdgcn_s_setprio(0);

    // P = exp2(s) directly; pack 4 consecutive j as 2 u32 (truncate-to-bf16).
    // Single P slot per wave: su-sequential write->read (wave-local DS ordering; verified).
    bf16x8 pf[4][2];
#pragma unroll
    for (int su = 0; su < 4; su++) {
      char* Pb = (char*)&Pl[wave][0];
#pragma unroll
      for (int nt = 0; nt < 4; nt++) {
        float p0 = __builtin_amdgcn_exp2f(sf[su][nt][0]);
        float p1 = __builtin_amdgcn_exp2f(sf[su][nt][1]);
        float p2 = __builtin_amdgcn_exp2f(sf[su][nt][2]);
        float p3 = __builtin_amdgcn_exp2f(sf[su][nt][3]);
        uint32_t w0 = (fbits(p0) >> 16) | (fbits(p1) & 0xffff0000u);
        uint32_t w1 = (fbits(p2) >> 16) | (fbits(p3) & 0xffff0000u);
        *(uint2*)(Pb + poff[nt]) = make_uint2(w0, w1);
      }
#pragma unroll
      for (int kc = 0; kc < 2; kc++) pf[su][kc] = *(const bf16x8*)(Pb + pread[kc]);
    }

    // O += P V ; l += P * ones   (all su share vf)
    __builtin_amdgcn_s_setprio(1);
#pragma unroll
    for (int dt = 0; dt < 4; dt++) {
      bf16x8 vf0 = *(const bf16x8*)&Vs[buf][lg][dt * 16 + lr][0];
      bf16x8 vf1 = *(const bf16x8*)&Vs[buf][4 + lg][dt * 16 + lr][0];
#pragma unroll
      for (int su = 0; su < 4; su++) {
        of[su][dt] = __builtin_amdgcn_mfma_f32_16x16x32_bf16(pf[su][0], vf0, of[su][dt], 0, 0, 0);
        of[su][dt] = __builtin_amdgcn_mfma_f32_16x16x32_bf16(pf[su][1], vf1, of[su][dt], 0, 0, 0);
      }
    }
#pragma unroll
    for (int su = 0; su < 4; su++) {
      of_sum[su] = __builtin_amdgcn_mfma_f32_16x16x32_bf16(pf[su][0], vones, of_sum[su], 0, 0, 0);
      of_sum[su] = __builtin_amdgcn_mfma_f32_16x16x32_bf16(pf[su][1], vones, of_sum[su], 0, 0, 0);
    }
    __builtin_amdgcn_s_setprio(0);

    __syncthreads();   // drains stage vmcnt + frag lgkmcnt; safe to swap buffers
    buf ^= 1;
  }
#undef ATTN_STAGE

  // epilogue: unnormalized partials into the half's buffer (rows b*4096+q)
  ushort_t* Opw = (half ? O1 : O0) + (size_t)b * 4096 * 512;
#pragma unroll
  for (int su = 0; su < 4; su++) {
#pragma unroll
    for (int dt = 0; dt < 4; dt++)
#pragma unroll
      for (int r = 0; r < 4; r++) {
        int q = qbase + su * 16 + lg * 4 + r;
        Opw[(size_t)q * 512 + h * 64 + dt * 16 + lr] = f2bf(of[su][dt][r]);
      }
    if (lr == 0) {
#pragma unroll
      for (int r = 0; r < 4; r++) {
        int q = qbase + su * 16 + lg * 4 + r;
        lpart[(((size_t)half * 2 + b) * 8 + h) * 4096 + q] = of_sum[su][r];
      }
    }
  }
}

// ---------------- merge partials: O = (O0+O1)/(l0+l1) ----------------
__global__ __launch_bounds__(128) void k_merge(const ushort_t* __restrict__ O0,
                                               const ushort_t* __restrict__ O1,
                                               const float* __restrict__ lpart,
                                               ushort_t* __restrict__ Ob) {
  const int row = blockIdx.x;          // b*4096 + q
  const int t = threadIdx.x;
  const int col = t * 4;
  const int b = row >> 12, q = row & 4095;
  const int h = col >> 6;
  float l = lpart[(((size_t)0 * 2 + b) * 8 + h) * 4096 + q] +
            lpart[(((size_t)1 * 2 + b) * 8 + h) * 4096 + q];
  float inv = 1.0f / l;
  ushort4 a0 = *(const ushort4*)(O0 + (size_t)row * 512 + col);
  ushort4 a1 = *(const ushort4*)(O1 + (size_t)row * 512 + col);
  ushort4 o;
  o.x = f2bf((bf2f(a0.x) + bf2f(a1.x)) * inv);
  o.y = f2bf((bf2f(a0.y) + bf2f(a1.y)) * inv);
  o.z = f2bf((bf2f(a0.z) + bf2f(a1.z)) * inv);
  o.w = f2bf((bf2f(a0.w) + bf2f(a1.w)) * inv);
  *(ushort4*)(Ob + (size_t)row * 512 + col) = o;
}

// ---------------- LayerNorm + residual ----------------
__global__ __launch_bounds__(256) void k_ln(const ushort_t* __restrict__ ypre,
                                            const float* __restrict__ x,
                                            const float* __restrict__ gamma,
                                            const float* __restrict__ beta,
                                            float* __restrict__ out) {
  __shared__ float red[8];
  const int row = blockIdx.x, t = threadIdx.x;
  const ushort_t* yr = ypre + (size_t)row * 1024;
  ushort4 u = *(const ushort4*)(yr + t * 4);
  float v0 = bf2f(u.x), v1 = bf2f(u.y), v2 = bf2f(u.z), v3 = bf2f(u.w);
  float s = v0 + v1 + v2 + v3;
  float sq = v0 * v0 + v1 * v1 + v2 * v2 + v3 * v3;
#pragma unroll
  for (int m = 32; m; m >>= 1) { s += __shfl_xor(s, m, 64); sq += __shfl_xor(sq, m, 64); }
  if ((t & 63) == 0) { red[t >> 6] = s; red[4 + (t >> 6)] = sq; }
  __syncthreads();
  s = red[0] + red[1] + red[2] + red[3];
  sq = red[4] + red[5] + red[6] + red[7];
  float mu = s * (1.f / 1024.f);
  float var = sq * (1.f / 1024.f) - mu * mu;
  float inv = rsqrtf(var + 1e-5f);
  int c = t * 4;
  float4 xf = *(const float4*)(x + (size_t)row * 1024 + c);
  float4 o;
  o.x = ((v0 - mu) * inv * gamma[c + 0] + beta[c + 0] + xf.x) * RSQRT2_F;
  o.y = ((v1 - mu) * inv * gamma[c + 1] + beta[c + 1] + xf.y) * RSQRT2_F;
  o.z = ((v2 - mu) * inv * gamma[c + 2] + beta[c + 2] + xf.z) * RSQRT2_F;
  o.w = ((v3 - mu) * inv * gamma[c + 3] + beta[c + 3] + xf.w) * RSQRT2_F;
  *(float4*)(out + (size_t)row * 1024 + c) = o;
}

extern "C" void kernel_launch(void* const* d_in, const int* in_sizes, int n_in,
                              void* d_out, int out_size, void* d_ws, size_t ws_size,
                              hipStream_t stream) {
  (void)in_sizes; (void)n_in; (void)out_size; (void)ws_size;
  const float* x     = (const float*)d_in[0];
  const float* Wqk   = (const float*)d_in[1];
  const float* bqk   = (const float*)d_in[2];
  const float* Wv    = (const float*)d_in[3];
  const float* bv    = (const float*)d_in[4];
  const float* Wout  = (const float*)d_in[5];
  const float* bout  = (const float*)d_in[6];
  const float* gamma = (const float*)d_in[7];
  const float* beta  = (const float*)d_in[8];
  float* out = (float*)d_out;

  char* ws = (char*)d_ws;
  size_t off = 0;
  auto alloc = [&](size_t bytes) {
    off = (off + 255) & ~(size_t)255;
    void* p = ws + off;
    off += bytes;
    return p;
  };
  ushort_t* xb    = (ushort_t*)alloc(8192ull * 1024 * 2);   // O0,O1 partials after GEMM0; ypre after merge
  ushort_t* Wqkvt = (ushort_t*)alloc(1536ull * 1024 * 2);
  float*    biasA = (float*)   alloc(1536ull * 4);
  ushort_t* Woutt = (ushort_t*)alloc(1024ull * 512 * 2);
  ushort_t* Qb    = (ushort_t*)alloc(8192ull * 512 * 2);    // Q; merged O after attn
  ushort_t* Kbuf  = (ushort_t*)alloc(8192ull * 512 * 2);
  ushort_t* Vtb   = (ushort_t*)alloc(1024ull * 4096 * 2);
  float*    lpart = (float*)   alloc(2ull * 2 * 8 * 4096 * 4);
  ushort_t* O0    = xb;                    // half 0 (first 8MB of xb)
  ushort_t* O1    = xb + 8192ull * 512;    // half 1 (second 8MB of xb)
  ushort_t* Obm   = Qb;                    // merged O (Qb dead after attn)
  ushort_t* ypre  = xb;                    // GEMM1 output (xb dead after merge)

  k_cvt_x<<<8192, 256, 0, stream>>>(x, xb);
  k_build_wqkv<<<dim3(4, 1536), 256, 0, stream>>>(Wqk, bqk, Wv, bv, Wqkvt, biasA);
  k_build_wout<<<dim3(2, 1024), 256, 0, stream>>>(Wout, Woutt);
  k_gemm_bt<0><<<dim3(64, 12), 256, 0, stream>>>(xb, Wqkvt, biasA, Qb, Kbuf, Vtb, 8192, 1536, 1024);
  k_attn<<<512, 256, 0, stream>>>(Qb, Kbuf, Vtb, O0, O1, lpart);
  k_merge<<<8192, 128, 0, stream>>>(O0, O1, lpart, Obm);
  k_gemm_bt<1><<<dim3(64, 8), 256, 0, stream>>>(Obm, Woutt, bout, ypre, nullptr, nullptr, 8192, 1024, 512);
  k_ln<<<8192, 256, 0, stream>>>(ypre, x, gamma, beta, out);
}

// Round 20
// 202.163 us; speedup vs baseline: 1.0778x; 1.0000x over previous
//
#include <hip/hip_runtime.h>
#include <stdint.h>

typedef short bf16x8 __attribute__((ext_vector_type(8)));   // 8 bf16 in 4 VGPRs
typedef float f32x4 __attribute__((ext_vector_type(4)));
typedef unsigned short ushort_t;

#define RSQRT2_F 0.70710678118654752440f
#define QSCALE_F 0.18033688011114382f   /* 0.125 * log2(e) */

__device__ __forceinline__ ushort_t f2bf(float f) {
  union { float f; uint32_t u; } c; c.f = f;
  uint32_t u = c.u;
  uint32_t r = (u + 0x7fffu + ((u >> 16) & 1u)) >> 16;   // RNE
  return (ushort_t)r;
}
__device__ __forceinline__ float bf2f(ushort_t u) {
  union { uint32_t u; float f; } c; c.u = ((uint32_t)u) << 16;
  return c.f;
}
__device__ __forceinline__ uint32_t fbits(float f) {
  union { float f; uint32_t u; } c; c.f = f; return c.u;
}

__device__ __forceinline__ void gload_lds16(const void* g, void* l) {
  __builtin_amdgcn_global_load_lds(
      (const __attribute__((address_space(1))) void*)g,
      (__attribute__((address_space(3))) void*)l, 16, 0, 0);
}

// ---------------- converts ----------------
__global__ __launch_bounds__(256) void k_cvt_x(const float* __restrict__ x,
                                               ushort_t* __restrict__ xb) {
  int i = (blockIdx.x * 256 + threadIdx.x) * 4;
  float4 f = *(const float4*)(x + i);
  ushort4 o;
  o.x = f2bf(f.x); o.y = f2bf(f.y); o.z = f2bf(f.z); o.w = f2bf(f.w);
  *(ushort4*)(xb + i) = o;
}

// Wt layout: [1536][1024]; rows 0..511 = Q cols (scaled by 0.125*log2e), 512..1023 = K, 1024..1535 = V
__global__ __launch_bounds__(256) void k_build_wqkv(const float* __restrict__ Wqk,
                                                    const float* __restrict__ bqk,
                                                    const float* __restrict__ Wv,
                                                    const float* __restrict__ bv,
                                                    ushort_t* __restrict__ Wt,
                                                    float* __restrict__ biasAll) {
  int k = blockIdx.x * 256 + threadIdx.x;  // 0..1023
  int n = blockIdx.y;                      // 0..1535
  float w, bb;
  if (n < 512)       { w = Wqk[(size_t)k * 1024 + 2 * n] * QSCALE_F;     bb = bqk[2 * n] * QSCALE_F; }
  else if (n < 1024) { w = Wqk[(size_t)k * 1024 + 2 * (n - 512) + 1];    bb = bqk[2 * (n - 512) + 1]; }
  else               { w = Wv[(size_t)k * 512 + (n - 1024)];             bb = bv[n - 1024]; }
  Wt[(size_t)n * 1024 + k] = f2bf(w);
  if (k == 0) biasAll[n] = bb;
}

__global__ __launch_bounds__(256) void k_build_wout(const float* __restrict__ Wout,
                                                    ushort_t* __restrict__ Wt) {
  int k = blockIdx.x * 256 + threadIdx.x;  // 0..511
  int n = blockIdx.y;                      // 0..1023
  Wt[(size_t)n * 512 + k] = f2bf(Wout[(size_t)k * 1024 + n]);
}

// ---------------- GEMM: C[M,N] = A[M,K](bf16) @ Bt[N,K](bf16)^T + bias ----------------
// r1/r14 measured-good structure (single-buffer LDS, BK=32, two barriers, scalar-store
// epilogue) + SUPERTILE block remap: consecutive 4*nby blocks cover a 4-m-tile A band x
// all n-tiles -> A band (1MB) + B panel stay L2-resident; A re-read drops ~12x.
template <int MODE>
__global__ __launch_bounds__(256) void k_gemm_bt(
    const ushort_t* __restrict__ A, const ushort_t* __restrict__ Bt,
    const float* __restrict__ bias,
    ushort_t* __restrict__ out0, ushort_t* __restrict__ out1, ushort_t* __restrict__ out2,
    int M, int N, int K) {
  __shared__ __align__(16) ushort_t As[4][128][8];  // [k/8][row][k%8]
  __shared__ __align__(16) ushort_t Bs[4][128][8];
  const int t = threadIdx.x;
  const int lane = t & 63;
  const int wave = t >> 6;

  // supertile remap (pure reorder; correctness-invariant)
  const int id = blockIdx.y * gridDim.x + blockIdx.x;   // x fastest in dispatch
  const int nby = gridDim.y;
  const int per = 4 * nby;
  const int sid = id / per, w = id % per;
  const int mt = sid * 4 + (w & 3), nt = w >> 2;
  const int m0 = mt * 128, n0 = nt * 128;

  const int wm = (wave >> 1) * 64, wn = (wave & 1) * 64;
  const int lg = lane >> 4, lr = lane & 15;

  const int srow = t & 127, sg = t >> 7;  // staging: row 0..127, g0 0..1
  ushort_t* lA0 = &As[sg][srow][0];
  ushort_t* lA1 = &As[sg + 2][srow][0];
  ushort_t* lB0 = &Bs[sg][srow][0];
  ushort_t* lB1 = &Bs[sg + 2][srow][0];
  const ushort_t* gA = A + (size_t)(m0 + srow) * K + sg * 8;
  const ushort_t* gB = Bt + (size_t)(n0 + srow) * K + sg * 8;

  f32x4 acc[4][4] = {};

  for (int k0 = 0; k0 < K; k0 += 32) {
    __syncthreads();
    gload_lds16(gA + k0, lA0);
    gload_lds16(gA + k0 + 16, lA1);
    gload_lds16(gB + k0, lB0);
    gload_lds16(gB + k0 + 16, lB1);
    __syncthreads();
    bf16x8 af[4], bfr[4];
#pragma unroll
    for (int mi = 0; mi < 4; mi++) af[mi] = *(const bf16x8*)&As[lg][wm + mi * 16 + lr][0];
#pragma unroll
    for (int ni = 0; ni < 4; ni++) bfr[ni] = *(const bf16x8*)&Bs[lg][wn + ni * 16 + lr][0];
#pragma unroll
    for (int mi = 0; mi < 4; mi++)
#pragma unroll
      for (int ni = 0; ni < 4; ni++)
        acc[mi][ni] = __builtin_amdgcn_mfma_f32_16x16x32_bf16(af[mi], bfr[ni], acc[mi][ni], 0, 0, 0);
  }

#pragma unroll
  for (int mi = 0; mi < 4; mi++) {
    int rowb = m0 + wm + mi * 16 + (lane >> 4) * 4;
#pragma unroll
    for (int ni = 0; ni < 4; ni++) {
      int col = n0 + wn + ni * 16 + lr;
      float bc = bias[col];
#pragma unroll
      for (int reg = 0; reg < 4; reg++) {
        int row = rowb + reg;
        float v = acc[mi][ni][reg] + bc;
        if (MODE == 0) {
          if (col < 512) {
            out0[(size_t)row * 512 + col] = f2bf(v);
          } else if (col < 1024) {
            out1[(size_t)row * 512 + (col - 512)] = f2bf(v);
          } else {
            int hd = col - 1024;
            int bb = row >> 12, s = row & 4095;
            out2[((size_t)(bb << 9) + hd) * 4096 + s] = f2bf(v);
          }
        } else {
          out0[(size_t)row * 1024 + col] = f2bf(v);
        }
      }
    }
  }
}

// ---------------- flash attention (no-max; 4 waves x 64q; KVBLK=64; KV-split x2) ----------------
// r14's verified 89us kernel, byte-identical.
__global__ __launch_bounds__(256, 2) void k_attn(const ushort_t* __restrict__ Qb,
                                                 const ushort_t* __restrict__ Kb,
                                                 const ushort_t* __restrict__ Vt,
                                                 ushort_t* __restrict__ O0,
                                                 ushort_t* __restrict__ O1,
                                                 float* __restrict__ lpart) {
  __shared__ __align__(16) ushort_t Ks[2][8][64][8];   // [buf][d/8][j][d%8]  16KB
  __shared__ __align__(16) ushort_t Vs[2][8][64][8];   // [buf][j/8][d][j%8]  16KB
  __shared__ __align__(16) ushort_t Pl[4][1024];       // per-wave single slot  8KB
  const int S = 4096;
  const int t = threadIdx.x, lane = t & 63, wave = t >> 6;
  const int lg = lane >> 4, lr = lane & 15;

  const int bid = blockIdx.x;
  const int xcd = bid & 7, idx = bid >> 3;           // idx 0..63
  const int bh = (xcd << 1) | (idx >> 5);            // 0..15, locked to one XCD
  const int rem = idx & 31;
  const int qb = rem >> 1;                            // 0..15 (256-q block)
  const int half = rem & 1;                           // KV half
  const int b = bh >> 3, h = bh & 7;
  const int qbase = qb * 256 + wave * 64;
  const int kvbase = half * 2048;

  // Q fragments for all four su (scale+log2e pre-folded into W_q)
  bf16x8 qf[4][2];
#pragma unroll
  for (int su = 0; su < 4; su++) {
    const ushort_t* qp = Qb + ((size_t)(b * S + qbase + su * 16 + lr)) * 512 + h * 64 + lg * 8;
    qf[su][0] = *(const bf16x8*)qp;
    qf[su][1] = *(const bf16x8*)(qp + 32);
  }

  // staging (256 threads): thread t -> chunk (cg = t>>6, cj = t&63); second issue cg+4
  const int cj = t & 63, cg = t >> 6;
  const ushort_t* gK = Kb + ((size_t)b * S + cj) * 512 + h * 64 + cg * 8;
  const ushort_t* gV = Vt + ((size_t)bh * 64 + cj) * 4096 + cg * 8;

  const bf16x8 vones = {(short)0x3F80, (short)0x3F80, (short)0x3F80, (short)0x3F80,
                        (short)0x3F80, (short)0x3F80, (short)0x3F80, (short)0x3F80};

  // precomputed P LDS offsets (loop-invariant)
  int poff[4], pread[2];
#pragma unroll
  for (int nt = 0; nt < 4; nt++) poff[nt] = (lr * 128 + nt * 32 + lg * 8) ^ ((lr & 7) << 4);
#pragma unroll
  for (int kc = 0; kc < 2; kc++) pread[kc] = (lr * 128 + kc * 64 + lg * 16) ^ ((lr & 7) << 4);

  f32x4 of[4][4] = {};
  f32x4 of_sum[4] = {};

#define ATTN_STAGE(kv0, bsel)                                         \
  do {                                                                \
    gload_lds16(gK + (size_t)(kv0) * 512, &Ks[bsel][cg][cj][0]);      \
    gload_lds16(gK + (size_t)(kv0) * 512 + 32, &Ks[bsel][cg + 4][cj][0]); \
    gload_lds16(gV + (kv0), &Vs[bsel][cg][cj][0]);                    \
    gload_lds16(gV + (kv0) + 32, &Vs[bsel][cg + 4][cj][0]);           \
  } while (0)

  ATTN_STAGE(kvbase, 0);
  __syncthreads();
  int buf = 0;

  for (int kv0 = kvbase; kv0 < kvbase + 2048; kv0 += 64) {
    if (kv0 + 64 < kvbase + 2048) ATTN_STAGE(kv0 + 64, buf ^ 1);

    // S^T = K Q^T : lane owns q = lr; holds j = nt*16 + lg*4 + r   (all su share kf)
    f32x4 sf[4][4];
    __builtin_amdgcn_s_setprio(1);
#pragma unroll
    for (int nt = 0; nt < 4; nt++) {
      bf16x8 kf0 = *(const bf16x8*)&Ks[buf][lg][nt * 16 + lr][0];
      bf16x8 kf1 = *(const bf16x8*)&Ks[buf][4 + lg][nt * 16 + lr][0];
#pragma unroll
      for (int su = 0; su < 4; su++) {
        f32x4 z = {};
        z = __builtin_amdgcn_mfma_f32_16x16x32_bf16(kf0, qf[su][0], z, 0, 0, 0);
        sf[su][nt] = __builtin_amdgcn_mfma_f32_16x16x32_bf16(kf1, qf[su][1], z, 0, 0, 0);
      }
    }
    __builtin_amdgcn_s_setprio(0);

    // P = exp2(s) directly; pack 4 consecutive j as 2 u32 (truncate-to-bf16).
    // Single P slot per wave: su-sequential write->read (wave-local DS ordering; verified).
    bf16x8 pf[4][2];
#pragma unroll
    for (int su = 0; su < 4; su++) {
      char* Pb = (char*)&Pl[wave][0];
#pragma unroll
      for (int nt = 0; nt < 4; nt++) {
        float p0 = __builtin_amdgcn_exp2f(sf[su][nt][0]);
        float p1 = __builtin_amdgcn_exp2f(sf[su][nt][1]);
        float p2 = __builtin_amdgcn_exp2f(sf[su][nt][2]);
        float p3 = __builtin_amdgcn_exp2f(sf[su][nt][3]);
        uint32_t w0 = (fbits(p0) >> 16) | (fbits(p1) & 0xffff0000u);
        uint32_t w1 = (fbits(p2) >> 16) | (fbits(p3) & 0xffff0000u);
        *(uint2*)(Pb + poff[nt]) = make_uint2(w0, w1);
      }
#pragma unroll
      for (int kc = 0; kc < 2; kc++) pf[su][kc] = *(const bf16x8*)(Pb + pread[kc]);
    }

    // O += P V ; l += P * ones   (all su share vf)
    __builtin_amdgcn_s_setprio(1);
#pragma unroll
    for (int dt = 0; dt < 4; dt++) {
      bf16x8 vf0 = *(const bf16x8*)&Vs[buf][lg][dt * 16 + lr][0];
      bf16x8 vf1 = *(const bf16x8*)&Vs[buf][4 + lg][dt * 16 + lr][0];
#pragma unroll
      for (int su = 0; su < 4; su++) {
        of[su][dt] = __builtin_amdgcn_mfma_f32_16x16x32_bf16(pf[su][0], vf0, of[su][dt], 0, 0, 0);
        of[su][dt] = __builtin_amdgcn_mfma_f32_16x16x32_bf16(pf[su][1], vf1, of[su][dt], 0, 0, 0);
      }
    }
#pragma unroll
    for (int su = 0; su < 4; su++) {
      of_sum[su] = __builtin_amdgcn_mfma_f32_16x16x32_bf16(pf[su][0], vones, of_sum[su], 0, 0, 0);
      of_sum[su] = __builtin_amdgcn_mfma_f32_16x16x32_bf16(pf[su][1], vones, of_sum[su], 0, 0, 0);
    }
    __builtin_amdgcn_s_setprio(0);

    __syncthreads();   // drains stage vmcnt + frag lgkmcnt; safe to swap buffers
    buf ^= 1;
  }
#undef ATTN_STAGE

  // epilogue: unnormalized partials into the half's buffer (rows b*4096+q)
  ushort_t* Opw = (half ? O1 : O0) + (size_t)b * 4096 * 512;
#pragma unroll
  for (int su = 0; su < 4; su++) {
#pragma unroll
    for (int dt = 0; dt < 4; dt++)
#pragma unroll
      for (int r = 0; r < 4; r++) {
        int q = qbase + su * 16 + lg * 4 + r;
        Opw[(size_t)q * 512 + h * 64 + dt * 16 + lr] = f2bf(of[su][dt][r]);
      }
    if (lr == 0) {
#pragma unroll
      for (int r = 0; r < 4; r++) {
        int q = qbase + su * 16 + lg * 4 + r;
        lpart[(((size_t)half * 2 + b) * 8 + h) * 4096 + q] = of_sum[su][r];
      }
    }
  }
}

// ---------------- merge partials: O = (O0+O1)/(l0+l1) ----------------
__global__ __launch_bounds__(128) void k_merge(const ushort_t* __restrict__ O0,
                                               const ushort_t* __restrict__ O1,
                                               const float* __restrict__ lpart,
                                               ushort_t* __restrict__ Ob) {
  const int row = blockIdx.x;          // b*4096 + q
  const int t = threadIdx.x;
  const int col = t * 4;
  const int b = row >> 12, q = row & 4095;
  const int h = col >> 6;
  float l = lpart[(((size_t)0 * 2 + b) * 8 + h) * 4096 + q] +
            lpart[(((size_t)1 * 2 + b) * 8 + h) * 4096 + q];
  float inv = 1.0f / l;
  ushort4 a0 = *(const ushort4*)(O0 + (size_t)row * 512 + col);
  ushort4 a1 = *(const ushort4*)(O1 + (size_t)row * 512 + col);
  ushort4 o;
  o.x = f2bf((bf2f(a0.x) + bf2f(a1.x)) * inv);
  o.y = f2bf((bf2f(a0.y) + bf2f(a1.y)) * inv);
  o.z = f2bf((bf2f(a0.z) + bf2f(a1.z)) * inv);
  o.w = f2bf((bf2f(a0.w) + bf2f(a1.w)) * inv);
  *(ushort4*)(Ob + (size_t)row * 512 + col) = o;
}

// ---------------- LayerNorm + residual ----------------
__global__ __launch_bounds__(256) void k_ln(const ushort_t* __restrict__ ypre,
                                            const float* __restrict__ x,
                                            const float* __restrict__ gamma,
                                            const float* __restrict__ beta,
                                            float* __restrict__ out) {
  __shared__ float red[8];
  const int row = blockIdx.x, t = threadIdx.x;
  const ushort_t* yr = ypre + (size_t)row * 1024;
  ushort4 u = *(const ushort4*)(yr + t * 4);
  float v0 = bf2f(u.x), v1 = bf2f(u.y), v2 = bf2f(u.z), v3 = bf2f(u.w);
  float s = v0 + v1 + v2 + v3;
  float sq = v0 * v0 + v1 * v1 + v2 * v2 + v3 * v3;
#pragma unroll
  for (int m = 32; m; m >>= 1) { s += __shfl_xor(s, m, 64); sq += __shfl_xor(sq, m, 64); }
  if ((t & 63) == 0) { red[t >> 6] = s; red[4 + (t >> 6)] = sq; }
  __syncthreads();
  s = red[0] + red[1] + red[2] + red[3];
  sq = red[4] + red[5] + red[6] + red[7];
  float mu = s * (1.f / 1024.f);
  float var = sq * (1.f / 1024.f) - mu * mu;
  float inv = rsqrtf(var + 1e-5f);
  int c = t * 4;
  float4 xf = *(const float4*)(x + (size_t)row * 1024 + c);
  float4 o;
  o.x = ((v0 - mu) * inv * gamma[c + 0] + beta[c + 0] + xf.x) * RSQRT2_F;
  o.y = ((v1 - mu) * inv * gamma[c + 1] + beta[c + 1] + xf.y) * RSQRT2_F;
  o.z = ((v2 - mu) * inv * gamma[c + 2] + beta[c + 2] + xf.z) * RSQRT2_F;
  o.w = ((v3 - mu) * inv * gamma[c + 3] + beta[c + 3] + xf.w) * RSQRT2_F;
  *(float4*)(out + (size_t)row * 1024 + c) = o;
}

extern "C" void kernel_launch(void* const* d_in, const int* in_sizes, int n_in,
                              void* d_out, int out_size, void* d_ws, size_t ws_size,
                              hipStream_t stream) {
  (void)in_sizes; (void)n_in; (void)out_size; (void)ws_size;
  const float* x     = (const float*)d_in[0];
  const float* Wqk   = (const float*)d_in[1];
  const float* bqk   = (const float*)d_in[2];
  const float* Wv    = (const float*)d_in[3];
  const float* bv    = (const float*)d_in[4];
  const float* Wout  = (const float*)d_in[5];
  const float* bout  = (const float*)d_in[6];
  const float* gamma = (const float*)d_in[7];
  const float* beta  = (const float*)d_in[8];
  float* out = (float*)d_out;

  char* ws = (char*)d_ws;
  size_t off = 0;
  auto alloc = [&](size_t bytes) {
    off = (off + 255) & ~(size_t)255;
    void* p = ws + off;
    off += bytes;
    return p;
  };
  ushort_t* xb    = (ushort_t*)alloc(8192ull * 1024 * 2);   // O0,O1 partials after GEMM0; ypre after merge
  ushort_t* Wqkvt = (ushort_t*)alloc(1536ull * 1024 * 2);
  float*    biasA = (float*)   alloc(1536ull * 4);
  ushort_t* Woutt = (ushort_t*)alloc(1024ull * 512 * 2);
  ushort_t* Qb    = (ushort_t*)alloc(8192ull * 512 * 2);    // Q; merged O after attn
  ushort_t* Kbuf  = (ushort_t*)alloc(8192ull * 512 * 2);
  ushort_t* Vtb   = (ushort_t*)alloc(1024ull * 4096 * 2);
  float*    lpart = (float*)   alloc(2ull * 2 * 8 * 4096 * 4);
  ushort_t* O0    = xb;                    // half 0 (first 8MB of xb)
  ushort_t* O1    = xb + 8192ull * 512;    // half 1 (second 8MB of xb)
  ushort_t* Obm   = Qb;                    // merged O (Qb dead after attn)
  ushort_t* ypre  = xb;                    // GEMM1 output (xb dead after merge)

  k_cvt_x<<<8192, 256, 0, stream>>>(x, xb);
  k_build_wqkv<<<dim3(4, 1536), 256, 0, stream>>>(Wqk, bqk, Wv, bv, Wqkvt, biasA);
  k_build_wout<<<dim3(2, 1024), 256, 0, stream>>>(Wout, Woutt);
  k_gemm_bt<0><<<dim3(64, 12), 256, 0, stream>>>(xb, Wqkvt, biasA, Qb, Kbuf, Vtb, 8192, 1536, 1024);
  k_attn<<<512, 256, 0, stream>>>(Qb, Kbuf, Vtb, O0, O1, lpart);
  k_merge<<<8192, 128, 0, stream>>>(O0, O1, lpart, Obm);
  k_gemm_bt<1><<<dim3(64, 8), 256, 0, stream>>>(Obm, Woutt, bout, ypre, nullptr, nullptr, 8192, 1024, 512);
  k_ln<<<8192, 256, 0, stream>>>(ypre, x, gamma, beta, out);
}

// Round 21
// 201.910 us; speedup vs baseline: 1.0792x; 1.0013x over previous
//
#include <hip/hip_runtime.h>
#include <stdint.h>

typedef short bf16x8 __attribute__((ext_vector_type(8)));   // 8 bf16 in 4 VGPRs
typedef float f32x4 __attribute__((ext_vector_type(4)));
typedef unsigned short ushort_t;

#define RSQRT2_F 0.70710678118654752440f
#define QSCALE_F 0.18033688011114382f   /* 0.125 * log2(e) */

__device__ __forceinline__ ushort_t f2bf(float f) {
  union { float f; uint32_t u; } c; c.f = f;
  uint32_t u = c.u;
  uint32_t r = (u + 0x7fffu + ((u >> 16) & 1u)) >> 16;   // RNE
  return (ushort_t)r;
}
__device__ __forceinline__ float bf2f(ushort_t u) {
  union { uint32_t u; float f; } c; c.u = ((uint32_t)u) << 16;
  return c.f;
}
__device__ __forceinline__ uint32_t fbits(float f) {
  union { float f; uint32_t u; } c; c.f = f; return c.u;
}

__device__ __forceinline__ void gload_lds16(const void* g, void* l) {
  __builtin_amdgcn_global_load_lds(
      (const __attribute__((address_space(1))) void*)g,
      (__attribute__((address_space(3))) void*)l, 16, 0, 0);
}

// ---------------- converts ----------------
__global__ __launch_bounds__(256) void k_cvt_x(const float* __restrict__ x,
                                               ushort_t* __restrict__ xb) {
  int i = (blockIdx.x * 256 + threadIdx.x) * 4;
  float4 f = *(const float4*)(x + i);
  ushort4 o;
  o.x = f2bf(f.x); o.y = f2bf(f.y); o.z = f2bf(f.z); o.w = f2bf(f.w);
  *(ushort4*)(xb + i) = o;
}

// Wt layout: [1536][1024]; rows 0..511 = Q cols (scaled by 0.125*log2e), 512..1023 = K, 1024..1535 = V
__global__ __launch_bounds__(256) void k_build_wqkv(const float* __restrict__ Wqk,
                                                    const float* __restrict__ bqk,
                                                    const float* __restrict__ Wv,
                                                    const float* __restrict__ bv,
                                                    ushort_t* __restrict__ Wt,
                                                    float* __restrict__ biasAll) {
  int k = blockIdx.x * 256 + threadIdx.x;  // 0..1023
  int n = blockIdx.y;                      // 0..1535
  float w, bb;
  if (n < 512)       { w = Wqk[(size_t)k * 1024 + 2 * n] * QSCALE_F;     bb = bqk[2 * n] * QSCALE_F; }
  else if (n < 1024) { w = Wqk[(size_t)k * 1024 + 2 * (n - 512) + 1];    bb = bqk[2 * (n - 512) + 1]; }
  else               { w = Wv[(size_t)k * 512 + (n - 1024)];             bb = bv[n - 1024]; }
  Wt[(size_t)n * 1024 + k] = f2bf(w);
  if (k == 0) biasAll[n] = bb;
}

__global__ __launch_bounds__(256) void k_build_wout(const float* __restrict__ Wout,
                                                    ushort_t* __restrict__ Wt) {
  int k = blockIdx.x * 256 + threadIdx.x;  // 0..511
  int n = blockIdx.y;                      // 0..1023
  Wt[(size_t)n * 512 + k] = f2bf(Wout[(size_t)k * 1024 + n]);
}

// ---------------- GEMM: C[M,N] = A[M,K](bf16) @ Bt[N,K](bf16)^T + bias ----------------
// r1/r14 measured-good structure (single-buffer LDS, BK=32, two barriers, scalar-store
// epilogue) + SUPERTILE block remap: consecutive 4*nby blocks cover a 4-m-tile A band x
// all n-tiles -> A band (1MB) + B panel stay L2-resident; A re-read drops ~12x.
template <int MODE>
__global__ __launch_bounds__(256) void k_gemm_bt(
    const ushort_t* __restrict__ A, const ushort_t* __restrict__ Bt,
    const float* __restrict__ bias,
    ushort_t* __restrict__ out0, ushort_t* __restrict__ out1, ushort_t* __restrict__ out2,
    int M, int N, int K) {
  __shared__ __align__(16) ushort_t As[4][128][8];  // [k/8][row][k%8]
  __shared__ __align__(16) ushort_t Bs[4][128][8];
  const int t = threadIdx.x;
  const int lane = t & 63;
  const int wave = t >> 6;

  // supertile remap (pure reorder; correctness-invariant)
  const int id = blockIdx.y * gridDim.x + blockIdx.x;   // x fastest in dispatch
  const int nby = gridDim.y;
  const int per = 4 * nby;
  const int sid = id / per, w = id % per;
  const int mt = sid * 4 + (w & 3), nt = w >> 2;
  const int m0 = mt * 128, n0 = nt * 128;

  const int wm = (wave >> 1) * 64, wn = (wave & 1) * 64;
  const int lg = lane >> 4, lr = lane & 15;

  const int srow = t & 127, sg = t >> 7;  // staging: row 0..127, g0 0..1
  ushort_t* lA0 = &As[sg][srow][0];
  ushort_t* lA1 = &As[sg + 2][srow][0];
  ushort_t* lB0 = &Bs[sg][srow][0];
  ushort_t* lB1 = &Bs[sg + 2][srow][0];
  const ushort_t* gA = A + (size_t)(m0 + srow) * K + sg * 8;
  const ushort_t* gB = Bt + (size_t)(n0 + srow) * K + sg * 8;

  f32x4 acc[4][4] = {};

  for (int k0 = 0; k0 < K; k0 += 32) {
    __syncthreads();
    gload_lds16(gA + k0, lA0);
    gload_lds16(gA + k0 + 16, lA1);
    gload_lds16(gB + k0, lB0);
    gload_lds16(gB + k0 + 16, lB1);
    __syncthreads();
    bf16x8 af[4], bfr[4];
#pragma unroll
    for (int mi = 0; mi < 4; mi++) af[mi] = *(const bf16x8*)&As[lg][wm + mi * 16 + lr][0];
#pragma unroll
    for (int ni = 0; ni < 4; ni++) bfr[ni] = *(const bf16x8*)&Bs[lg][wn + ni * 16 + lr][0];
#pragma unroll
    for (int mi = 0; mi < 4; mi++)
#pragma unroll
      for (int ni = 0; ni < 4; ni++)
        acc[mi][ni] = __builtin_amdgcn_mfma_f32_16x16x32_bf16(af[mi], bfr[ni], acc[mi][ni], 0, 0, 0);
  }

#pragma unroll
  for (int mi = 0; mi < 4; mi++) {
    int rowb = m0 + wm + mi * 16 + (lane >> 4) * 4;
#pragma unroll
    for (int ni = 0; ni < 4; ni++) {
      int col = n0 + wn + ni * 16 + lr;
      float bc = bias[col];
#pragma unroll
      for (int reg = 0; reg < 4; reg++) {
        int row = rowb + reg;
        float v = acc[mi][ni][reg] + bc;
        if (MODE == 0) {
          if (col < 512) {
            out0[(size_t)row * 512 + col] = f2bf(v);
          } else if (col < 1024) {
            out1[(size_t)row * 512 + (col - 512)] = f2bf(v);
          } else {
            int hd = col - 1024;
            int bb = row >> 12, s = row & 4095;
            out2[((size_t)(bb << 9) + hd) * 4096 + s] = f2bf(v);
          }
        } else {
          out0[(size_t)row * 1024 + col] = f2bf(v);
        }
      }
    }
  }
}

// ---------------- flash attention (no-max; 4 waves x 64q; KVBLK=64; KV-split x2) ----------------
// r14's verified 89us kernel, byte-identical.
__global__ __launch_bounds__(256, 2) void k_attn(const ushort_t* __restrict__ Qb,
                                                 const ushort_t* __restrict__ Kb,
                                                 const ushort_t* __restrict__ Vt,
                                                 ushort_t* __restrict__ O0,
                                                 ushort_t* __restrict__ O1,
                                                 float* __restrict__ lpart) {
  __shared__ __align__(16) ushort_t Ks[2][8][64][8];   // [buf][d/8][j][d%8]  16KB
  __shared__ __align__(16) ushort_t Vs[2][8][64][8];   // [buf][j/8][d][j%8]  16KB
  __shared__ __align__(16) ushort_t Pl[4][1024];       // per-wave single slot  8KB
  const int S = 4096;
  const int t = threadIdx.x, lane = t & 63, wave = t >> 6;
  const int lg = lane >> 4, lr = lane & 15;

  const int bid = blockIdx.x;
  const int xcd = bid & 7, idx = bid >> 3;           // idx 0..63
  const int bh = (xcd << 1) | (idx >> 5);            // 0..15, locked to one XCD
  const int rem = idx & 31;
  const int qb = rem >> 1;                            // 0..15 (256-q block)
  const int half = rem & 1;                           // KV half
  const int b = bh >> 3, h = bh & 7;
  const int qbase = qb * 256 + wave * 64;
  const int kvbase = half * 2048;

  // Q fragments for all four su (scale+log2e pre-folded into W_q)
  bf16x8 qf[4][2];
#pragma unroll
  for (int su = 0; su < 4; su++) {
    const ushort_t* qp = Qb + ((size_t)(b * S + qbase + su * 16 + lr)) * 512 + h * 64 + lg * 8;
    qf[su][0] = *(const bf16x8*)qp;
    qf[su][1] = *(const bf16x8*)(qp + 32);
  }

  // staging (256 threads): thread t -> chunk (cg = t>>6, cj = t&63); second issue cg+4
  const int cj = t & 63, cg = t >> 6;
  const ushort_t* gK = Kb + ((size_t)b * S + cj) * 512 + h * 64 + cg * 8;
  const ushort_t* gV = Vt + ((size_t)bh * 64 + cj) * 4096 + cg * 8;

  const bf16x8 vones = {(short)0x3F80, (short)0x3F80, (short)0x3F80, (short)0x3F80,
                        (short)0x3F80, (short)0x3F80, (short)0x3F80, (short)0x3F80};

  // precomputed P LDS offsets (loop-invariant)
  int poff[4], pread[2];
#pragma unroll
  for (int nt = 0; nt < 4; nt++) poff[nt] = (lr * 128 + nt * 32 + lg * 8) ^ ((lr & 7) << 4);
#pragma unroll
  for (int kc = 0; kc < 2; kc++) pread[kc] = (lr * 128 + kc * 64 + lg * 16) ^ ((lr & 7) << 4);

  f32x4 of[4][4] = {};
  f32x4 of_sum[4] = {};

#define ATTN_STAGE(kv0, bsel)                                         \
  do {                                                                \
    gload_lds16(gK + (size_t)(kv0) * 512, &Ks[bsel][cg][cj][0]);      \
    gload_lds16(gK + (size_t)(kv0) * 512 + 32, &Ks[bsel][cg + 4][cj][0]); \
    gload_lds16(gV + (kv0), &Vs[bsel][cg][cj][0]);                    \
    gload_lds16(gV + (kv0) + 32, &Vs[bsel][cg + 4][cj][0]);           \
  } while (0)

  ATTN_STAGE(kvbase, 0);
  __syncthreads();
  int buf = 0;

  for (int kv0 = kvbase; kv0 < kvbase + 2048; kv0 += 64) {
    if (kv0 + 64 < kvbase + 2048) ATTN_STAGE(kv0 + 64, buf ^ 1);

    // S^T = K Q^T : lane owns q = lr; holds j = nt*16 + lg*4 + r   (all su share kf)
    f32x4 sf[4][4];
    __builtin_amdgcn_s_setprio(1);
#pragma unroll
    for (int nt = 0; nt < 4; nt++) {
      bf16x8 kf0 = *(const bf16x8*)&Ks[buf][lg][nt * 16 + lr][0];
      bf16x8 kf1 = *(const bf16x8*)&Ks[buf][4 + lg][nt * 16 + lr][0];
#pragma unroll
      for (int su = 0; su < 4; su++) {
        f32x4 z = {};
        z = __builtin_amdgcn_mfma_f32_16x16x32_bf16(kf0, qf[su][0], z, 0, 0, 0);
        sf[su][nt] = __builtin_amdgcn_mfma_f32_16x16x32_bf16(kf1, qf[su][1], z, 0, 0, 0);
      }
    }
    __builtin_amdgcn_s_setprio(0);

    // P = exp2(s) directly; pack 4 consecutive j as 2 u32 (truncate-to-bf16).
    // Single P slot per wave: su-sequential write->read (wave-local DS ordering; verified).
    bf16x8 pf[4][2];
#pragma unroll
    for (int su = 0; su < 4; su++) {
      char* Pb = (char*)&Pl[wave][0];
#pragma unroll
      for (int nt = 0; nt < 4; nt++) {
        float p0 = __builtin_amdgcn_exp2f(sf[su][nt][0]);
        float p1 = __builtin_amdgcn_exp2f(sf[su][nt][1]);
        float p2 = __builtin_amdgcn_exp2f(sf[su][nt][2]);
        float p3 = __builtin_amdgcn_exp2f(sf[su][nt][3]);
        uint32_t w0 = (fbits(p0) >> 16) | (fbits(p1) & 0xffff0000u);
        uint32_t w1 = (fbits(p2) >> 16) | (fbits(p3) & 0xffff0000u);
        *(uint2*)(Pb + poff[nt]) = make_uint2(w0, w1);
      }
#pragma unroll
      for (int kc = 0; kc < 2; kc++) pf[su][kc] = *(const bf16x8*)(Pb + pread[kc]);
    }

    // O += P V ; l += P * ones   (all su share vf)
    __builtin_amdgcn_s_setprio(1);
#pragma unroll
    for (int dt = 0; dt < 4; dt++) {
      bf16x8 vf0 = *(const bf16x8*)&Vs[buf][lg][dt * 16 + lr][0];
      bf16x8 vf1 = *(const bf16x8*)&Vs[buf][4 + lg][dt * 16 + lr][0];
#pragma unroll
      for (int su = 0; su < 4; su++) {
        of[su][dt] = __builtin_amdgcn_mfma_f32_16x16x32_bf16(pf[su][0], vf0, of[su][dt], 0, 0, 0);
        of[su][dt] = __builtin_amdgcn_mfma_f32_16x16x32_bf16(pf[su][1], vf1, of[su][dt], 0, 0, 0);
      }
    }
#pragma unroll
    for (int su = 0; su < 4; su++) {
      of_sum[su] = __builtin_amdgcn_mfma_f32_16x16x32_bf16(pf[su][0], vones, of_sum[su], 0, 0, 0);
      of_sum[su] = __builtin_amdgcn_mfma_f32_16x16x32_bf16(pf[su][1], vones, of_sum[su], 0, 0, 0);
    }
    __builtin_amdgcn_s_setprio(0);

    __syncthreads();   // drains stage vmcnt + frag lgkmcnt; safe to swap buffers
    buf ^= 1;
  }
#undef ATTN_STAGE

  // epilogue: unnormalized partials into the half's buffer (rows b*4096+q)
  ushort_t* Opw = (half ? O1 : O0) + (size_t)b * 4096 * 512;
#pragma unroll
  for (int su = 0; su < 4; su++) {
#pragma unroll
    for (int dt = 0; dt < 4; dt++)
#pragma unroll
      for (int r = 0; r < 4; r++) {
        int q = qbase + su * 16 + lg * 4 + r;
        Opw[(size_t)q * 512 + h * 64 + dt * 16 + lr] = f2bf(of[su][dt][r]);
      }
    if (lr == 0) {
#pragma unroll
      for (int r = 0; r < 4; r++) {
        int q = qbase + su * 16 + lg * 4 + r;
        lpart[(((size_t)half * 2 + b) * 8 + h) * 4096 + q] = of_sum[su][r];
      }
    }
  }
}

// ---------------- merge partials: O = (O0+O1)/(l0+l1) ----------------
__global__ __launch_bounds__(128) void k_merge(const ushort_t* __restrict__ O0,
                                               const ushort_t* __restrict__ O1,
                                               const float* __restrict__ lpart,
                                               ushort_t* __restrict__ Ob) {
  const int row = blockIdx.x;          // b*4096 + q
  const int t = threadIdx.x;
  const int col = t * 4;
  const int b = row >> 12, q = row & 4095;
  const int h = col >> 6;
  float l = lpart[(((size_t)0 * 2 + b) * 8 + h) * 4096 + q] +
            lpart[(((size_t)1 * 2 + b) * 8 + h) * 4096 + q];
  float inv = 1.0f / l;
  ushort4 a0 = *(const ushort4*)(O0 + (size_t)row * 512 + col);
  ushort4 a1 = *(const ushort4*)(O1 + (size_t)row * 512 + col);
  ushort4 o;
  o.x = f2bf((bf2f(a0.x) + bf2f(a1.x)) * inv);
  o.y = f2bf((bf2f(a0.y) + bf2f(a1.y)) * inv);
  o.z = f2bf((bf2f(a0.z) + bf2f(a1.z)) * inv);
  o.w = f2bf((bf2f(a0.w) + bf2f(a1.w)) * inv);
  *(ushort4*)(Ob + (size_t)row * 512 + col) = o;
}

// ---------------- LayerNorm + residual ----------------
__global__ __launch_bounds__(256) void k_ln(const ushort_t* __restrict__ ypre,
                                            const float* __restrict__ x,
                                            const float* __restrict__ gamma,
                                            const float* __restrict__ beta,
                                            float* __restrict__ out) {
  __shared__ float red[8];
  const int row = blockIdx.x, t = threadIdx.x;
  const ushort_t* yr = ypre + (size_t)row * 1024;
  ushort4 u = *(const ushort4*)(yr + t * 4);
  float v0 = bf2f(u.x), v1 = bf2f(u.y), v2 = bf2f(u.z), v3 = bf2f(u.w);
  float s = v0 + v1 + v2 + v3;
  float sq = v0 * v0 + v1 * v1 + v2 * v2 + v3 * v3;
#pragma unroll
  for (int m = 32; m; m >>= 1) { s += __shfl_xor(s, m, 64); sq += __shfl_xor(sq, m, 64); }
  if ((t & 63) == 0) { red[t >> 6] = s; red[4 + (t >> 6)] = sq; }
  __syncthreads();
  s = red[0] + red[1] + red[2] + red[3];
  sq = red[4] + red[5] + red[6] + red[7];
  float mu = s * (1.f / 1024.f);
  float var = sq * (1.f / 1024.f) - mu * mu;
  float inv = rsqrtf(var + 1e-5f);
  int c = t * 4;
  float4 xf = *(const float4*)(x + (size_t)row * 1024 + c);
  float4 o;
  o.x = ((v0 - mu) * inv * gamma[c + 0] + beta[c + 0] + xf.x) * RSQRT2_F;
  o.y = ((v1 - mu) * inv * gamma[c + 1] + beta[c + 1] + xf.y) * RSQRT2_F;
  o.z = ((v2 - mu) * inv * gamma[c + 2] + beta[c + 2] + xf.z) * RSQRT2_F;
  o.w = ((v3 - mu) * inv * gamma[c + 3] + beta[c + 3] + xf.w) * RSQRT2_F;
  *(float4*)(out + (size_t)row * 1024 + c) = o;
}

extern "C" void kernel_launch(void* const* d_in, const int* in_sizes, int n_in,
                              void* d_out, int out_size, void* d_ws, size_t ws_size,
                              hipStream_t stream) {
  (void)in_sizes; (void)n_in; (void)out_size; (void)ws_size;
  const float* x     = (const float*)d_in[0];
  const float* Wqk   = (const float*)d_in[1];
  const float* bqk   = (const float*)d_in[2];
  const float* Wv    = (const float*)d_in[3];
  const float* bv    = (const float*)d_in[4];
  const float* Wout  = (const float*)d_in[5];
  const float* bout  = (const float*)d_in[6];
  const float* gamma = (const float*)d_in[7];
  const float* beta  = (const float*)d_in[8];
  float* out = (float*)d_out;

  char* ws = (char*)d_ws;
  size_t off = 0;
  auto alloc = [&](size_t bytes) {
    off = (off + 255) & ~(size_t)255;
    void* p = ws + off;
    off += bytes;
    return p;
  };
  ushort_t* xb    = (ushort_t*)alloc(8192ull * 1024 * 2);   // O0,O1 partials after GEMM0; ypre after merge
  ushort_t* Wqkvt = (ushort_t*)alloc(1536ull * 1024 * 2);
  float*    biasA = (float*)   alloc(1536ull * 4);
  ushort_t* Woutt = (ushort_t*)alloc(1024ull * 512 * 2);
  ushort_t* Qb    = (ushort_t*)alloc(8192ull * 512 * 2);    // Q; merged O after attn
  ushort_t* Kbuf  = (ushort_t*)alloc(8192ull * 512 * 2);
  ushort_t* Vtb   = (ushort_t*)alloc(1024ull * 4096 * 2);
  float*    lpart = (float*)   alloc(2ull * 2 * 8 * 4096 * 4);
  ushort_t* O0    = xb;                    // half 0 (first 8MB of xb)
  ushort_t* O1    = xb + 8192ull * 512;    // half 1 (second 8MB of xb)
  ushort_t* Obm   = Qb;                    // merged O (Qb dead after attn)
  ushort_t* ypre  = xb;                    // GEMM1 output (xb dead after merge)

  k_cvt_x<<<8192, 256, 0, stream>>>(x, xb);
  k_build_wqkv<<<dim3(4, 1536), 256, 0, stream>>>(Wqk, bqk, Wv, bv, Wqkvt, biasA);
  k_build_wout<<<dim3(2, 1024), 256, 0, stream>>>(Wout, Woutt);
  k_gemm_bt<0><<<dim3(64, 12), 256, 0, stream>>>(xb, Wqkvt, biasA, Qb, Kbuf, Vtb, 8192, 1536, 1024);
  k_attn<<<512, 256, 0, stream>>>(Qb, Kbuf, Vtb, O0, O1, lpart);
  k_merge<<<8192, 128, 0, stream>>>(O0, O1, lpart, Obm);
  k_gemm_bt<1><<<dim3(64, 8), 256, 0, stream>>>(Obm, Woutt, bout, ypre, nullptr, nullptr, 8192, 1024, 512);
  k_ln<<<8192, 256, 0, stream>>>(ypre, x, gamma, beta, out);
}